// Round 11
// baseline (43.351 us; speedup 1.0000x reference)
//
#include <hip/hip_runtime.h>
#include <hip/hip_bf16.h>
#include <float.h>

// Problem constants (from reference setup_inputs)
#define B_  4
#define C_  256
#define H_  50
#define W_  50
#define R_  300
#define PH_ 7
#define PW_ 7
#define S_  (H_ * W_)        // 2500
#define Q_  (PH_ * PW_)      // 49
#define SC_ (S_ * C_)        // 640000 floats per batch image
#define ARRN (B_ * SC_)      // 2,560,000 floats per table
#define CQ_  64              // channels per pool block
#define NCQ  (C_ / CQ_)      // 4
#define NWG_POOL (R_ * NCQ)  // 1200 (divisible by 8)

// ---------------------------------------------------------------------------
// Kernel K1: transpose fm [B,C,S] -> fmT [B,S,C], build span-4 table
//   P4[b,s,c] = max over w..min(w+3, W-1) (row-clamped) of fm
// AND (one extra block) spatially sort the 300 ROIs by (batch, y-band,
// x-band) via O(n^2) rank -> perm[], so the XCD-chunked pool blocks give
// each XCD a CLUSTERED set of ROIs whose table lines fit its 4 MB L2.
// ---------------------------------------------------------------------------
__global__ __launch_bounds__(256) void transpose_tables(
    const float* __restrict__ fm,   // [B, C, S]
    float* __restrict__ fmT,        // [B, S, C]
    float* __restrict__ P4,         // [B, S, C]
    const float* __restrict__ rois, // [R, 5]
    int* __restrict__ perm)         // [R] sorted-roi -> original-roi
{
    __shared__ float tile[64][69];
    __shared__ int   skey[R_];

    // ---- sort block (blockIdx.x == 40) ----
    if (blockIdx.x == 40) {
        if (blockIdx.y != 0 || blockIdx.z != 0) return;
        const int t = threadIdx.y * 64 + threadIdx.x;   // 0..255
        for (int i = t; i < R_; i += 256) {
            const float* rp = rois + i * 5;
            int b  = (int)rp[4];
            int x0 = (int)rintf(rp[0]); x0 = min(max(x0, 0), W_ - 1);
            int y0 = (int)rintf(rp[1]); y0 = min(max(y0, 0), H_ - 1);
            skey[i] = (b << 8) | ((y0 >> 3) << 4) | (x0 >> 3);
        }
        __syncthreads();
        for (int i = t; i < R_; i += 256) {
            const int k = skey[i];
            int rank = 0;
            for (int j = 0; j < R_; ++j) {
                const int kj = skey[j];
                rank += (kj < k) || (kj == k && j < i);   // deterministic, bijective
            }
            perm[rank] = i;
        }
        return;
    }

    // ---- transpose + table blocks (blockIdx.x 0..39) ----
    const int b  = blockIdx.z;
    const int c0 = blockIdx.y * 64;           // 256/64 = 4
    const int s0 = blockIdx.x * 64;           // 40 tiles cover 2500

    const int tx = threadIdx.x;               // 0..63 (lane)
    const int ty = threadIdx.y;               // 0..3  (wave)

    if (s0 + tx < S_) {
        #pragma unroll
        for (int j = 0; j < 16; ++j) {
            const int c = c0 + ty + j * 4;
            tile[ty + j * 4][tx] = fm[((size_t)b * C_ + c) * S_ + (s0 + tx)];
        }
    }
    if (tx < 4 && s0 + 64 + tx < S_) {
        #pragma unroll
        for (int j = 0; j < 16; ++j) {
            const int c = c0 + ty + j * 4;
            tile[ty + j * 4][64 + tx] = fm[((size_t)b * C_ + c) * S_ + (s0 + 64 + tx)];
        }
    }
    __syncthreads();

    #pragma unroll
    for (int j = 0; j < 16; ++j) {
        const int s = s0 + ty + j * 4;
        if (s < S_) {
            const int ls  = ty + j * 4;
            const int w   = s % W_;                    // wave-uniform
            const int rem = W_ - 1 - w;                // valid same-row nbrs
            const float v0 = tile[tx][ls];
            float p4 = v0;
            if (rem >= 1) p4 = fmaxf(p4, tile[tx][ls + 1]);
            if (rem >= 2) p4 = fmaxf(p4, tile[tx][ls + 2]);
            if (rem >= 3) p4 = fmaxf(p4, tile[tx][ls + 3]);

            const size_t o = ((size_t)b * S_ + s) * C_ + (c0 + tx);
            fmT[o] = v0;
            P4[o]  = p4;
        }
    }
}

// ---------------------------------------------------------------------------
// Block-uniform ROI decode (SPATIAL_SCALE == 1.0); matches reference exactly.
// ---------------------------------------------------------------------------
__device__ __forceinline__ void roi_decode(const float* __restrict__ rois, int r,
                                           int& b, int& x0, int& y0,
                                           int& roi_w, int& roi_h)
{
    const float* rp = rois + r * 5;
    b = (int)rp[4];                          // trunc, matches astype(int32)
    // jnp.round == round-half-to-even == rintf
    x0      = (int)rintf(rp[0]);
    y0      = (int)rintf(rp[1]);
    int x1  = (int)rintf(rp[2]);
    int y1  = (int)rintf(rp[3]);
    x0 = min(max(x0, 0), W_ - 1);
    x1 = min(max(x1, 0), W_ - 1);
    y0 = min(max(y0, 0), H_ - 1);
    y1 = min(max(y1, 0), H_ - 1);
    x1 = max(x1, x0 + 1);
    y1 = max(y1, y0 + 1);
    roi_w = x1 - x0;                         // >= 1  (bin widths  <= 8)
    roi_h = y1 - y0;                         // >= 1  (bin heights <= 8)
}

// ---------------------------------------------------------------------------
// Branchless per-bin pooling, WH = block-uniform max bin height (template).
// ww>=4: two P4 anchors (ws covers ws..ws+3 <= we-1; we-4 >= ws) -> exact
// union for 4<=ww<=8. ww<=3: three fmT anchors ws, min(ws+1,we-1), we-1
// (ww=1: all dup; ww=2: {ws,ws+1,ws+1}; ww=3: {ws,ws+1,ws+2}) -> exact.
// Rows: min(hs+kh, he-1) in-window clamp, duplicates don't change a max.
// All offsets int32 (< 2.56M). Wave-uniform control only.
// ---------------------------------------------------------------------------
template<int WH>
__device__ __forceinline__ void pool_bins(
    const float* __restrict__ fmT, const float* __restrict__ P4,
    float* __restrict__ buf,
    int wv, int lane, int imgC,
    int x0, int y0, int roi_w, int roi_h)
{
    const int start = wv * 12 + (wv ? 1 : 0);
    const int qlast = wv * 12 + 12;

    #pragma unroll 2
    for (int k = 0; k < 13; ++k) {
        int q = start + k;
        q = (q > qlast) ? qlast : q;
        const int ph = q / PW_;
        const int pw = q - ph * PW_;
        const int ws = x0 + (pw * roi_w) / PW_;
        const int we = x0 + ((pw + 1) * roi_w + PW_ - 1) / PW_;
        const int hs = y0 + (ph * roi_h) / PH_;
        const int he = y0 + ((ph + 1) * roi_h + PH_ - 1) / PH_;
        const int ww = we - ws;              // 1..8

        float m = -FLT_MAX;
        if (ww >= 4) {                       // wave-uniform branch
            const int cA = ws * C_, cB = (we - 4) * C_;
            float va[WH], vb[WH];
            #pragma unroll
            for (int kh = 0; kh < WH; ++kh) {
                int row = hs + kh;
                row = (row > he - 1) ? (he - 1) : row;
                const int ro = imgC + row * (W_ * C_);
                va[kh] = P4[ro + cA];
                vb[kh] = P4[ro + cB];
            }
            #pragma unroll
            for (int kh = 0; kh < WH; ++kh)
                m = fmaxf(m, fmaxf(va[kh], vb[kh]));
        } else {
            const int cA = ws * C_;
            const int cB = min(ws + 1, we - 1) * C_;
            const int cC = (we - 1) * C_;
            float va[WH], vb[WH], vc[WH];
            #pragma unroll
            for (int kh = 0; kh < WH; ++kh) {
                int row = hs + kh;
                row = (row > he - 1) ? (he - 1) : row;
                const int ro = imgC + row * (W_ * C_);
                va[kh] = fmT[ro + cA];
                vb[kh] = fmT[ro + cB];
                vc[kh] = fmT[ro + cC];
            }
            #pragma unroll
            for (int kh = 0; kh < WH; ++kh)
                m = fmaxf(m, fmaxf(va[kh], fmaxf(vb[kh], vc[kh])));
        }
        buf[q * 65 + lane] = m;
    }
}

// ---------------------------------------------------------------------------
// Kernel K2: fused pool. Block = (sorted-roi, 64-ch quarter) -> 1200 blocks,
// 4 waves. XCD-chunked swizzle over SORTED ids -> each XCD gets ~37
// spatially-clustered ROIs -> table working set ~L2-resident.
// Staged in padded LDS [49][65]; block-exclusive contiguous 12.5 KB write.
// ---------------------------------------------------------------------------
__global__ __launch_bounds__(256) void roi_pool_tables(
    const float* __restrict__ fmT,   // [B, S, C]
    const float* __restrict__ P4,    // [B, S, C]
    const float* __restrict__ rois,  // [R, 5]
    const int* __restrict__ perm,    // [R]
    float* __restrict__ out)         // [R, C, Q]
{
    __shared__ float buf[Q_ * 65];           // 12740 B

    const int bid = blockIdx.x;
    const int swz = (bid & 7) * (NWG_POOL / 8) + (bid >> 3);   // 1200 % 8 == 0
    const int rid = swz >> 2;                // sorted roi index
    const int c0  = (swz & (NCQ - 1)) * CQ_;
    const int r   = perm[rid];               // original roi (uniform scalar load)

    const int t    = threadIdx.x;
    const int wv   = t >> 6;
    const int lane = t & 63;

    int b, x0, y0, roi_w, roi_h;
    roi_decode(rois, r, b, x0, y0, roi_w, roi_h);

    // exact block-uniform max bin height
    int whmax = 1;
    #pragma unroll
    for (int i = 0; i < PH_; ++i) {
        const int hs = (i * roi_h) / PH_;
        const int he = ((i + 1) * roi_h + PH_ - 1) / PH_;
        whmax = max(whmax, he - hs);
    }

    const int imgC = b * SC_ + c0 + lane;    // < 2.56M, fits int32

    switch (whmax) {                         // block-uniform dispatch
        case 1: pool_bins<1>(fmT, P4, buf, wv, lane, imgC, x0, y0, roi_w, roi_h); break;
        case 2: pool_bins<2>(fmT, P4, buf, wv, lane, imgC, x0, y0, roi_w, roi_h); break;
        case 3: pool_bins<3>(fmT, P4, buf, wv, lane, imgC, x0, y0, roi_w, roi_h); break;
        case 4: pool_bins<4>(fmT, P4, buf, wv, lane, imgC, x0, y0, roi_w, roi_h); break;
        case 5: pool_bins<5>(fmT, P4, buf, wv, lane, imgC, x0, y0, roi_w, roi_h); break;
        case 6: pool_bins<6>(fmT, P4, buf, wv, lane, imgC, x0, y0, roi_w, roi_h); break;
        case 7: pool_bins<7>(fmT, P4, buf, wv, lane, imgC, x0, y0, roi_w, roi_h); break;
        default: pool_bins<8>(fmT, P4, buf, wv, lane, imgC, x0, y0, roi_w, roi_h); break;
    }
    __syncthreads();

    // block-exclusive coalesced write: out[r, c0..c0+64, 0..49)
    float* outp = out + ((size_t)r * C_ + c0) * Q_;
    #pragma unroll
    for (int k = 0; k < 13; ++k) {
        const int e = k * 256 + t;
        if (e < CQ_ * Q_) {
            const int cl = e / Q_;
            const int q  = e - cl * Q_;
            outp[e] = buf[q * 65 + cl];
        }
    }
}

// ---------------------------------------------------------------------------
// Fallback (ws too small): round-1 thread-per-output kernel (proven, 42.7 us).
// ---------------------------------------------------------------------------
__global__ __launch_bounds__(256) void roi_pool_naive(
    const float* __restrict__ fm,    // [B, C, H, W]
    const float* __restrict__ rois,
    float* __restrict__ out)
{
    const int total = R_ * C_ * Q_;
    int t = blockIdx.x * blockDim.x + threadIdx.x;
    if (t >= total) return;
    int q   = t % Q_;
    int tmp = t / Q_;
    int pw  = q % PW_;
    int ph  = q / PW_;
    int c   = tmp % C_;
    int r   = tmp / C_;

    int b, x0, y0, roi_w, roi_h;
    roi_decode(rois, r, b, x0, y0, roi_w, roi_h);

    const int ws = x0 + (pw * roi_w) / PW_;
    const int we = x0 + ((pw + 1) * roi_w + PW_ - 1) / PW_;
    const int hs = y0 + (ph * roi_h) / PH_;
    const int he = y0 + ((ph + 1) * roi_h + PH_ - 1) / PH_;

    const float* p = fm + ((size_t)(b * C_ + c)) * S_;
    float m = -FLT_MAX;
    for (int h = hs; h < he; ++h)
        for (int w = ws; w < we; ++w)
            m = fmaxf(m, p[h * W_ + w]);
    out[t] = m;
}

extern "C" void kernel_launch(void* const* d_in, const int* in_sizes, int n_in,
                              void* d_out, int out_size, void* d_ws, size_t ws_size,
                              hipStream_t stream)
{
    const float* fm   = (const float*)d_in[0];  // [4,256,50,50]
    const float* rois = (const float*)d_in[1];  // [300,5]
    float* out        = (float*)d_out;          // [300,256,7,7]

    const size_t NEED = 2 * (size_t)ARRN * sizeof(float) + 4096;   // 20.48 MB + perm

    if (ws_size >= NEED) {
        float* fmT = (float*)d_ws;
        float* P4  = fmT + ARRN;
        int*   perm = (int*)(P4 + ARRN);
        {
            dim3 grid(41, C_ / 64, B_);          // 40 transpose tiles + 1 sort block
            dim3 block(64, 4, 1);
            transpose_tables<<<grid, block, 0, stream>>>(fm, fmT, P4, rois, perm);
        }
        roi_pool_tables<<<NWG_POOL, 256, 0, stream>>>(fmT, P4, rois, perm, out);
    } else {
        const int total = R_ * C_ * Q_;
        roi_pool_naive<<<(total + 255) / 256, 256, 0, stream>>>(fm, rois, out);
    }
}

// Round 12
// 42.186 us; speedup vs baseline: 1.0276x; 1.0276x over previous
//
#include <hip/hip_runtime.h>
#include <hip/hip_bf16.h>
#include <float.h>

// Problem constants (from reference setup_inputs)
#define B_  4
#define C_  256
#define H_  50
#define W_  50
#define R_  300
#define PH_ 7
#define PW_ 7
#define S_  (H_ * W_)        // 2500
#define Q_  (PH_ * PW_)      // 49
#define SC_ (S_ * C_)        // 640000 floats per batch image
#define ARRN (B_ * SC_)      // 2,560,000 floats per table
#define CQ_  64              // channels per pool block
#define NCQ  (C_ / CQ_)      // 4
#define NWG_POOL (R_ * NCQ)  // 1200 (divisible by 8)

// ---------------------------------------------------------------------------
// Kernel K1: transpose fm [B,C,S] -> fmT [B,S,C], build span tables
//   P2[b,s,c] = max over w..min(w+1, W-1) (row-clamped) of fm
//   P4[b,s,c] = max over w..min(w+3, W-1) (row-clamped) of fm
// AND (one extra block) spatially sort the 300 ROIs by (batch, y-band,
// x-band) via O(n^2) rank -> perm[], so K2's XCD-chunked blocks give each
// XCD a CLUSTERED set of ROIs whose table lines fit its 4 MB L2.
// ---------------------------------------------------------------------------
__global__ __launch_bounds__(256) void transpose_tables(
    const float* __restrict__ fm,   // [B, C, S]
    float* __restrict__ fmT,        // [B, S, C]
    float* __restrict__ P2,         // [B, S, C]
    float* __restrict__ P4,         // [B, S, C]
    const float* __restrict__ rois, // [R, 5]
    int* __restrict__ perm)         // [R] sorted-roi -> original-roi
{
    __shared__ float tile[64][69];
    __shared__ int   skey[R_];

    // ---- sort block (blockIdx.x == 40) ----
    if (blockIdx.x == 40) {
        if (blockIdx.y != 0 || blockIdx.z != 0) return;
        const int t = threadIdx.y * 64 + threadIdx.x;   // 0..255
        for (int i = t; i < R_; i += 256) {
            const float* rp = rois + i * 5;
            int b  = (int)rp[4];
            int x0 = (int)rintf(rp[0]); x0 = min(max(x0, 0), W_ - 1);
            int y0 = (int)rintf(rp[1]); y0 = min(max(y0, 0), H_ - 1);
            skey[i] = (b << 8) | ((y0 >> 3) << 4) | (x0 >> 3);
        }
        __syncthreads();
        for (int i = t; i < R_; i += 256) {
            const int k = skey[i];
            int rank = 0;
            for (int j = 0; j < R_; ++j) {
                const int kj = skey[j];
                rank += (kj < k) || (kj == k && j < i);   // deterministic, bijective
            }
            perm[rank] = i;
        }
        return;
    }

    // ---- transpose + table blocks (blockIdx.x 0..39) ----
    const int b  = blockIdx.z;
    const int c0 = blockIdx.y * 64;           // 256/64 = 4
    const int s0 = blockIdx.x * 64;           // 40 tiles cover 2500

    const int tx = threadIdx.x;               // 0..63 (lane)
    const int ty = threadIdx.y;               // 0..3  (wave)

    if (s0 + tx < S_) {
        #pragma unroll
        for (int j = 0; j < 16; ++j) {
            const int c = c0 + ty + j * 4;
            tile[ty + j * 4][tx] = fm[((size_t)b * C_ + c) * S_ + (s0 + tx)];
        }
    }
    if (tx < 4 && s0 + 64 + tx < S_) {
        #pragma unroll
        for (int j = 0; j < 16; ++j) {
            const int c = c0 + ty + j * 4;
            tile[ty + j * 4][64 + tx] = fm[((size_t)b * C_ + c) * S_ + (s0 + 64 + tx)];
        }
    }
    __syncthreads();

    #pragma unroll
    for (int j = 0; j < 16; ++j) {
        const int s = s0 + ty + j * 4;
        if (s < S_) {
            const int ls  = ty + j * 4;
            const int w   = s % W_;                    // wave-uniform
            const int rem = W_ - 1 - w;                // valid same-row nbrs
            const float v0 = tile[tx][ls];
            float p2 = (rem >= 1) ? fmaxf(v0, tile[tx][ls + 1]) : v0;
            float p4 = p2;
            if (rem >= 2) p4 = fmaxf(p4, tile[tx][ls + 2]);
            if (rem >= 3) p4 = fmaxf(p4, tile[tx][ls + 3]);

            const size_t o = ((size_t)b * S_ + s) * C_ + (c0 + tx);
            fmT[o] = v0;
            P2[o]  = p2;
            P4[o]  = p4;
        }
    }
}

// ---------------------------------------------------------------------------
// Block-uniform ROI decode (SPATIAL_SCALE == 1.0); matches reference exactly.
// ---------------------------------------------------------------------------
__device__ __forceinline__ void roi_decode(const float* __restrict__ rois, int r,
                                           int& b, int& x0, int& y0,
                                           int& roi_w, int& roi_h)
{
    const float* rp = rois + r * 5;
    b = (int)rp[4];                          // trunc, matches astype(int32)
    // jnp.round == round-half-to-even == rintf
    x0      = (int)rintf(rp[0]);
    y0      = (int)rintf(rp[1]);
    int x1  = (int)rintf(rp[2]);
    int y1  = (int)rintf(rp[3]);
    x0 = min(max(x0, 0), W_ - 1);
    x1 = min(max(x1, 0), W_ - 1);
    y0 = min(max(y0, 0), H_ - 1);
    y1 = min(max(y1, 0), H_ - 1);
    x1 = max(x1, x0 + 1);
    y1 = max(y1, y0 + 1);
    roi_w = x1 - x0;                         // >= 1  (bin widths  <= 8)
    roi_h = y1 - y0;                         // >= 1  (bin heights <= 8)
}

// ---------------------------------------------------------------------------
// Branchless per-bin pooling, WH = block-uniform max bin height (template).
// Width via span tables: sp = 4/2/1 -> anchors ws and we-sp cover exactly
// [ws,we) for any ww 1..8. Rows: min(hs+kh, he-1) in-window clamp ->
// duplicates, max unchanged. UNROLL 2: <= 32 values in flight, no spills.
// All offsets int32 (< 2.56M). Wave-uniform control only.
// Bin->wave: contiguous ranges w0:0-12, w1:13-24, w2:25-36, w3:37-48; the
// within-wave clamp re-computes the wave's own last bin (same LDS value,
// no cross-wave aliasing).
// ---------------------------------------------------------------------------
template<int WH>
__device__ __forceinline__ void pool_bins(
    const float* __restrict__ fmT, const float* __restrict__ P2,
    const float* __restrict__ P4, float* __restrict__ buf,
    int wv, int lane, int imgC,
    int x0, int y0, int roi_w, int roi_h)
{
    const int start = wv * 12 + (wv ? 1 : 0);
    const int qlast = wv * 12 + 12;

    #pragma unroll 2
    for (int k = 0; k < 13; ++k) {
        int q = start + k;
        q = (q > qlast) ? qlast : q;
        const int ph = q / PW_;
        const int pw = q - ph * PW_;
        const int ws = x0 + (pw * roi_w) / PW_;
        const int we = x0 + ((pw + 1) * roi_w + PW_ - 1) / PW_;
        const int hs = y0 + (ph * roi_h) / PH_;
        const int he = y0 + ((ph + 1) * roi_h + PH_ - 1) / PH_;
        const int ww = we - ws;              // 1..8

        const int sp = (ww >= 4) ? 4 : ((ww >= 2) ? 2 : 1);
        const float* tb = (ww >= 4) ? P4 : ((ww >= 2) ? P2 : fmT);
        const int colB = we - sp;

        float va[WH], vb[WH];
        #pragma unroll
        for (int kh = 0; kh < WH; ++kh) {
            int row = hs + kh;
            row = (row > he - 1) ? (he - 1) : row;        // clamp (in-window)
            const int ro = imgC + row * (W_ * C_);
            va[kh] = tb[ro + ws * C_];
            vb[kh] = tb[ro + colB * C_];
        }
        float m = -FLT_MAX;
        #pragma unroll
        for (int kh = 0; kh < WH; ++kh)
            m = fmaxf(m, fmaxf(va[kh], vb[kh]));

        buf[q * 65 + lane] = m;
    }
}

// ---------------------------------------------------------------------------
// Kernel K2: fused pool. Block = (sorted-roi, 64-ch quarter) -> 1200 blocks,
// 4 waves. XCD-chunked swizzle over SORTED ids -> each XCD gets ~37
// spatially-clustered ROIs -> table working set ~L2-resident.
// Staged in padded LDS [49][65]; block-exclusive contiguous 12.5 KB write.
// ---------------------------------------------------------------------------
__global__ __launch_bounds__(256) void roi_pool_tables(
    const float* __restrict__ fmT,   // [B, S, C]
    const float* __restrict__ P2,    // [B, S, C]
    const float* __restrict__ P4,    // [B, S, C]
    const float* __restrict__ rois,  // [R, 5]
    const int* __restrict__ perm,    // [R]
    float* __restrict__ out)         // [R, C, Q]
{
    __shared__ float buf[Q_ * 65];           // 12740 B

    const int bid = blockIdx.x;
    const int swz = (bid & 7) * (NWG_POOL / 8) + (bid >> 3);   // 1200 % 8 == 0
    const int rid = swz >> 2;                // sorted roi index
    const int c0  = (swz & (NCQ - 1)) * CQ_;
    const int r   = perm[rid];               // original roi

    const int t    = threadIdx.x;
    const int wv   = t >> 6;
    const int lane = t & 63;

    int b, x0, y0, roi_w, roi_h;
    roi_decode(rois, r, b, x0, y0, roi_w, roi_h);

    // exact block-uniform max bin height
    int whmax = 1;
    #pragma unroll
    for (int i = 0; i < PH_; ++i) {
        const int hs = (i * roi_h) / PH_;
        const int he = ((i + 1) * roi_h + PH_ - 1) / PH_;
        whmax = max(whmax, he - hs);
    }

    const int imgC = b * SC_ + c0 + lane;    // < 2.56M, fits int32

    switch (whmax) {                         // block-uniform dispatch
        case 1: pool_bins<1>(fmT, P2, P4, buf, wv, lane, imgC, x0, y0, roi_w, roi_h); break;
        case 2: pool_bins<2>(fmT, P2, P4, buf, wv, lane, imgC, x0, y0, roi_w, roi_h); break;
        case 3: pool_bins<3>(fmT, P2, P4, buf, wv, lane, imgC, x0, y0, roi_w, roi_h); break;
        case 4: pool_bins<4>(fmT, P2, P4, buf, wv, lane, imgC, x0, y0, roi_w, roi_h); break;
        case 5: pool_bins<5>(fmT, P2, P4, buf, wv, lane, imgC, x0, y0, roi_w, roi_h); break;
        case 6: pool_bins<6>(fmT, P2, P4, buf, wv, lane, imgC, x0, y0, roi_w, roi_h); break;
        case 7: pool_bins<7>(fmT, P2, P4, buf, wv, lane, imgC, x0, y0, roi_w, roi_h); break;
        default: pool_bins<8>(fmT, P2, P4, buf, wv, lane, imgC, x0, y0, roi_w, roi_h); break;
    }
    __syncthreads();

    // block-exclusive coalesced write: out[r, c0..c0+64, 0..49)
    float* outp = out + ((size_t)r * C_ + c0) * Q_;
    #pragma unroll
    for (int k = 0; k < 13; ++k) {
        const int e = k * 256 + t;
        if (e < CQ_ * Q_) {
            const int cl = e / Q_;
            const int q  = e - cl * Q_;
            outp[e] = buf[q * 65 + cl];
        }
    }
}

// ---------------------------------------------------------------------------
// Fallback (ws too small): round-1 thread-per-output kernel (proven, 42.7 us).
// ---------------------------------------------------------------------------
__global__ __launch_bounds__(256) void roi_pool_naive(
    const float* __restrict__ fm,    // [B, C, H, W]
    const float* __restrict__ rois,
    float* __restrict__ out)
{
    const int total = R_ * C_ * Q_;
    int t = blockIdx.x * blockDim.x + threadIdx.x;
    if (t >= total) return;
    int q   = t % Q_;
    int tmp = t / Q_;
    int pw  = q % PW_;
    int ph  = q / PW_;
    int c   = tmp % C_;
    int r   = tmp / C_;

    int b, x0, y0, roi_w, roi_h;
    roi_decode(rois, r, b, x0, y0, roi_w, roi_h);

    const int ws = x0 + (pw * roi_w) / PW_;
    const int we = x0 + ((pw + 1) * roi_w + PW_ - 1) / PW_;
    const int hs = y0 + (ph * roi_h) / PH_;
    const int he = y0 + ((ph + 1) * roi_h + PH_ - 1) / PH_;

    const float* p = fm + ((size_t)(b * C_ + c)) * S_;
    float m = -FLT_MAX;
    for (int h = hs; h < he; ++h)
        for (int w = ws; w < we; ++w)
            m = fmaxf(m, p[h * W_ + w]);
    out[t] = m;
}

extern "C" void kernel_launch(void* const* d_in, const int* in_sizes, int n_in,
                              void* d_out, int out_size, void* d_ws, size_t ws_size,
                              hipStream_t stream)
{
    const float* fm   = (const float*)d_in[0];  // [4,256,50,50]
    const float* rois = (const float*)d_in[1];  // [300,5]
    float* out        = (float*)d_out;          // [300,256,7,7]

    const size_t NEED = 3 * (size_t)ARRN * sizeof(float) + 4096;   // 30.72 MB + perm

    if (ws_size >= NEED) {
        float* fmT  = (float*)d_ws;
        float* P2   = fmT + ARRN;
        float* P4   = P2 + ARRN;
        int*   perm = (int*)(P4 + ARRN);
        {
            dim3 grid(41, C_ / 64, B_);          // 40 transpose tiles + 1 sort block
            dim3 block(64, 4, 1);
            transpose_tables<<<grid, block, 0, stream>>>(fm, fmT, P2, P4, rois, perm);
        }
        roi_pool_tables<<<NWG_POOL, 256, 0, stream>>>(fmT, P2, P4, rois, perm, out);
    } else {
        const int total = R_ * C_ * Q_;
        roi_pool_naive<<<(total + 255) / 256, 256, 0, stream>>>(fm, rois, out);
    }
}

// Round 13
// 41.102 us; speedup vs baseline: 1.0547x; 1.0264x over previous
//
#include <hip/hip_runtime.h>
#include <hip/hip_bf16.h>
#include <float.h>

// Problem constants (from reference setup_inputs)
#define B_  4
#define C_  256
#define H_  50
#define W_  50
#define R_  300
#define PH_ 7
#define PW_ 7
#define S_  (H_ * W_)        // 2500
#define Q_  (PH_ * PW_)      // 49
#define SC_ (S_ * C_)        // 640000 floats per batch image
#define ARRN (B_ * SC_)      // 2,560,000 floats per table
#define CE_  32              // channels per pool block (eighth)
#define NCE  (C_ / CE_)      // 8 channel-eighths == NXCD
#define NWG_POOL (R_ * NCE)  // 2400

// ---------------------------------------------------------------------------
// Kernel K1 (R10-proven, sort removed): transpose fm [B,C,S] -> fmT [B,S,C],
// build span tables
//   P2[b,s,c] = max over w..min(w+1, W-1) (row-clamped) of fm
//   P4[b,s,c] = max over w..min(w+3, W-1) (row-clamped) of fm
// ---------------------------------------------------------------------------
__global__ __launch_bounds__(256) void transpose_tables(
    const float* __restrict__ fm,   // [B, C, S]
    float* __restrict__ fmT,        // [B, S, C]
    float* __restrict__ P2,         // [B, S, C]
    float* __restrict__ P4)         // [B, S, C]
{
    __shared__ float tile[64][69];

    const int b  = blockIdx.z;
    const int c0 = blockIdx.y * 64;           // 256/64 = 4
    const int s0 = blockIdx.x * 64;           // 40 tiles cover 2500

    const int tx = threadIdx.x;               // 0..63 (lane)
    const int ty = threadIdx.y;               // 0..3  (wave)

    if (s0 + tx < S_) {
        #pragma unroll
        for (int j = 0; j < 16; ++j) {
            const int c = c0 + ty + j * 4;
            tile[ty + j * 4][tx] = fm[((size_t)b * C_ + c) * S_ + (s0 + tx)];
        }
    }
    if (tx < 4 && s0 + 64 + tx < S_) {
        #pragma unroll
        for (int j = 0; j < 16; ++j) {
            const int c = c0 + ty + j * 4;
            tile[ty + j * 4][64 + tx] = fm[((size_t)b * C_ + c) * S_ + (s0 + 64 + tx)];
        }
    }
    __syncthreads();

    #pragma unroll
    for (int j = 0; j < 16; ++j) {
        const int s = s0 + ty + j * 4;
        if (s < S_) {
            const int ls  = ty + j * 4;
            const int w   = s % W_;                    // wave-uniform
            const int rem = W_ - 1 - w;                // valid same-row nbrs
            const float v0 = tile[tx][ls];
            float p2 = (rem >= 1) ? fmaxf(v0, tile[tx][ls + 1]) : v0;
            float p4 = p2;
            if (rem >= 2) p4 = fmaxf(p4, tile[tx][ls + 2]);
            if (rem >= 3) p4 = fmaxf(p4, tile[tx][ls + 3]);

            const size_t o = ((size_t)b * S_ + s) * C_ + (c0 + tx);
            fmT[o] = v0;
            P2[o]  = p2;
            P4[o]  = p4;
        }
    }
}

// ---------------------------------------------------------------------------
// Block-uniform ROI decode (SPATIAL_SCALE == 1.0); matches reference exactly.
// ---------------------------------------------------------------------------
__device__ __forceinline__ void roi_decode(const float* __restrict__ rois, int r,
                                           int& b, int& x0, int& y0,
                                           int& roi_w, int& roi_h)
{
    const float* rp = rois + r * 5;
    b = (int)rp[4];                          // trunc, matches astype(int32)
    // jnp.round == round-half-to-even == rintf
    x0      = (int)rintf(rp[0]);
    y0      = (int)rintf(rp[1]);
    int x1  = (int)rintf(rp[2]);
    int y1  = (int)rintf(rp[3]);
    x0 = min(max(x0, 0), W_ - 1);
    x1 = min(max(x1, 0), W_ - 1);
    y0 = min(max(y0, 0), H_ - 1);
    y1 = min(max(y1, 0), H_ - 1);
    x1 = max(x1, x0 + 1);
    y1 = max(y1, y0 + 1);
    roi_w = x1 - x0;                         // >= 1  (bin widths  <= 8)
    roi_h = y1 - y0;                         // >= 1  (bin heights <= 8)
}

// ---------------------------------------------------------------------------
// Per-bin pooling with lane = (channel, anchor-half): lanes 0-31 load column
// anchor A (= ws), lanes 32-63 anchor B (= we - sp) of the selected span
// table (identical math to R10: sp=4 -> P4, sp=2 -> P2, sp=1 -> fmT; the two
// anchors' spans union EXACTLY to [ws, we) for any ww in 1..8). One wave
// instruction loads both anchors for 32 channels. Vertical: WH row loads
// with in-window clamp row = min(hs+kh, he-1) (duplicates, max unchanged).
// Cross-half combine via __shfl_xor(m, 32). Wave wv handles q = wv + 2k.
// ---------------------------------------------------------------------------
template<int WH>
__device__ __forceinline__ void pool_bins_e(
    const float* __restrict__ fmT, const float* __restrict__ P2,
    const float* __restrict__ P4, float* __restrict__ buf,
    int wv, int lane, int imgCE,
    int x0, int y0, int roi_w, int roi_h)
{
    const int c    = lane & 31;              // channel within eighth
    const int half = lane >> 5;              // 0 = anchor A, 1 = anchor B

    #pragma unroll 2
    for (int k = 0; k < 25; ++k) {
        const int q = wv + 2 * k;
        if (q < Q_) {                        // wave-uniform
            const int ph = q / PW_;
            const int pw = q - ph * PW_;
            const int ws = x0 + (pw * roi_w) / PW_;
            const int we = x0 + ((pw + 1) * roi_w + PW_ - 1) / PW_;
            const int hs = y0 + (ph * roi_h) / PH_;
            const int he = y0 + ((ph + 1) * roi_h + PH_ - 1) / PH_;
            const int ww = we - ws;          // 1..8

            const int sp = (ww >= 4) ? 4 : ((ww >= 2) ? 2 : 1);
            const float* tb = (ww >= 4) ? P4 : ((ww >= 2) ? P2 : fmT);
            const int col = (half ? (we - sp) : ws) * C_;   // per-lane select

            float va[WH];
            #pragma unroll
            for (int kh = 0; kh < WH; ++kh) {
                int row = hs + kh;
                row = (row > he - 1) ? (he - 1) : row;      // clamp (in-window)
                va[kh] = tb[imgCE + row * (W_ * C_) + col];
            }
            float m = -FLT_MAX;
            #pragma unroll
            for (int kh = 0; kh < WH; ++kh)
                m = fmaxf(m, va[kh]);

            m = fmaxf(m, __shfl_xor(m, 32)); // combine anchor halves
            if (half == 0)
                buf[q * 33 + c] = m;
        }
    }
}

// ---------------------------------------------------------------------------
// Kernel K2: block = (roi, channel-eighth) -> 2400 blocks, 128 threads
// (2 waves). NO swizzle: hardware round-robin gives XCD = bid % 8 = eighth,
// so each XCD serves ONE 32-channel slice for ALL ROIs -> per-XCD table
// footprint 3 x 1.28 MB = 3.84 MB < 4 MB L2 -> reads L2-resident.
// Staged in padded LDS [49][33]; block-exclusive contiguous 6.1 KB write.
// ---------------------------------------------------------------------------
__global__ __launch_bounds__(128) void roi_pool_tables(
    const float* __restrict__ fmT,   // [B, S, C]
    const float* __restrict__ P2,    // [B, S, C]
    const float* __restrict__ P4,    // [B, S, C]
    const float* __restrict__ rois,  // [R, 5]
    float* __restrict__ out)         // [R, C, Q]
{
    __shared__ float buf[Q_ * 33];           // 6468 B

    const int bid = blockIdx.x;
    const int e   = bid & 7;                 // channel-eighth == XCD
    const int r   = bid >> 3;                // roi

    const int t    = threadIdx.x;            // 0..127
    const int wv   = t >> 6;                 // wave 0..1
    const int lane = t & 63;

    int b, x0, y0, roi_w, roi_h;
    roi_decode(rois, r, b, x0, y0, roi_w, roi_h);

    // exact block-uniform max bin height
    int whmax = 1;
    #pragma unroll
    for (int i = 0; i < PH_; ++i) {
        const int hs = (i * roi_h) / PH_;
        const int he = ((i + 1) * roi_h + PH_ - 1) / PH_;
        whmax = max(whmax, he - hs);
    }

    const int imgCE = b * SC_ + e * CE_ + (lane & 31);   // < 2.56M, fits int32

    switch (whmax) {                         // block-uniform dispatch
        case 1: pool_bins_e<1>(fmT, P2, P4, buf, wv, lane, imgCE, x0, y0, roi_w, roi_h); break;
        case 2: pool_bins_e<2>(fmT, P2, P4, buf, wv, lane, imgCE, x0, y0, roi_w, roi_h); break;
        case 3: pool_bins_e<3>(fmT, P2, P4, buf, wv, lane, imgCE, x0, y0, roi_w, roi_h); break;
        case 4: pool_bins_e<4>(fmT, P2, P4, buf, wv, lane, imgCE, x0, y0, roi_w, roi_h); break;
        case 5: pool_bins_e<5>(fmT, P2, P4, buf, wv, lane, imgCE, x0, y0, roi_w, roi_h); break;
        case 6: pool_bins_e<6>(fmT, P2, P4, buf, wv, lane, imgCE, x0, y0, roi_w, roi_h); break;
        case 7: pool_bins_e<7>(fmT, P2, P4, buf, wv, lane, imgCE, x0, y0, roi_w, roi_h); break;
        default: pool_bins_e<8>(fmT, P2, P4, buf, wv, lane, imgCE, x0, y0, roi_w, roi_h); break;
    }
    __syncthreads();

    // block-exclusive coalesced write: out[r, e*32 .. e*32+32, 0..49) = 6272 B
    float* outp = out + ((size_t)r * C_ + e * CE_) * Q_;
    #pragma unroll
    for (int k = 0; k < 13; ++k) {           // ceil(32*49 / 128) = 13
        const int idx = k * 128 + t;
        if (idx < CE_ * Q_) {
            const int cl = idx / Q_;
            const int q  = idx - cl * Q_;
            outp[idx] = buf[q * 33 + cl];    // stride 33: conflict-free
        }
    }
}

// ---------------------------------------------------------------------------
// Fallback (ws too small): round-1 thread-per-output kernel (proven, 42.7 us).
// ---------------------------------------------------------------------------
__global__ __launch_bounds__(256) void roi_pool_naive(
    const float* __restrict__ fm,    // [B, C, H, W]
    const float* __restrict__ rois,
    float* __restrict__ out)
{
    const int total = R_ * C_ * Q_;
    int t = blockIdx.x * blockDim.x + threadIdx.x;
    if (t >= total) return;
    int q   = t % Q_;
    int tmp = t / Q_;
    int pw  = q % PW_;
    int ph  = q / PW_;
    int c   = tmp % C_;
    int r   = tmp / C_;

    int b, x0, y0, roi_w, roi_h;
    roi_decode(rois, r, b, x0, y0, roi_w, roi_h);

    const int ws = x0 + (pw * roi_w) / PW_;
    const int we = x0 + ((pw + 1) * roi_w + PW_ - 1) / PW_;
    const int hs = y0 + (ph * roi_h) / PH_;
    const int he = y0 + ((ph + 1) * roi_h + PH_ - 1) / PH_;

    const float* p = fm + ((size_t)(b * C_ + c)) * S_;
    float m = -FLT_MAX;
    for (int h = hs; h < he; ++h)
        for (int w = ws; w < we; ++w)
            m = fmaxf(m, p[h * W_ + w]);
    out[t] = m;
}

extern "C" void kernel_launch(void* const* d_in, const int* in_sizes, int n_in,
                              void* d_out, int out_size, void* d_ws, size_t ws_size,
                              hipStream_t stream)
{
    const float* fm   = (const float*)d_in[0];  // [4,256,50,50]
    const float* rois = (const float*)d_in[1];  // [300,5]
    float* out        = (float*)d_out;          // [300,256,7,7]

    const size_t NEED = 3 * (size_t)ARRN * sizeof(float);   // 30.72 MB

    if (ws_size >= NEED) {
        float* fmT = (float*)d_ws;
        float* P2  = fmT + ARRN;
        float* P4  = P2 + ARRN;
        {
            dim3 grid(40, C_ / 64, B_);          // 40 s-tiles x 4 c-tiles x 4 batch
            dim3 block(64, 4, 1);
            transpose_tables<<<grid, block, 0, stream>>>(fm, fmT, P2, P4);
        }
        roi_pool_tables<<<NWG_POOL, 128, 0, stream>>>(fmT, P2, P4, rois, out);
    } else {
        const int total = R_ * C_ * Q_;
        roi_pool_naive<<<(total + 255) / 256, 256, 0, stream>>>(fm, rois, out);
    }
}

// Round 14
// 33.829 us; speedup vs baseline: 1.2815x; 1.2150x over previous
//
#include <hip/hip_runtime.h>
#include <hip/hip_bf16.h>
#include <float.h>

// Problem constants (from reference setup_inputs)
#define B_  4
#define C_  256
#define H_  50
#define W_  50
#define R_  300
#define PH_ 7
#define PW_ 7
#define S_  (H_ * W_)        // 2500
#define Q_  (PH_ * PW_)      // 49
#define SC_ (S_ * C_)        // 640000 floats per batch image
#define ARRN (B_ * SC_)      // 2,560,000 floats per table
#define CQ_  64              // channels per pool block
#define NCQ  (C_ / CQ_)      // 4
#define NWG_POOL (R_ * NCQ)  // 1200 (divisible by 8)

// ---------------------------------------------------------------------------
// Kernel K1 (REWRITTEN for dense writes): transpose fm [B,C,S] -> fmT [B,S,C]
// and build span tables P2 (w..w+1 row-clamped max), P4 (w..w+3).
// Tile = 32 s-cols (+3 halo) x ALL 256 channels; LDS [256][37] (37.9 KB,
// store-phase bank = (5c+ls)%32, gcd(5,32)=1 -> conflict-free 2/bank).
// Store phase: threads span the full channel dim -> each (s, table) write is
// 1024 B CONTIGUOUS (vs 256-of-1024 strided before) -> dense HBM bursts.
// ---------------------------------------------------------------------------
__global__ __launch_bounds__(512) void transpose_tables(
    const float* __restrict__ fm,   // [B, C, S]
    float* __restrict__ fmT,        // [B, S, C]
    float* __restrict__ P2,         // [B, S, C]
    float* __restrict__ P4)         // [B, S, C]
{
    __shared__ float tile[256][37];           // 37,888 B

    const int b  = blockIdx.y;
    const int s0 = blockIdx.x * 32;           // 79 tiles cover 2500

    const int t    = threadIdx.x;             // 0..511
    const int wv   = t >> 6;                  // wave 0..7
    const int lane = t & 63;

    // load: wave wv handles channel rows c = wv + 8k; lanes 0..34 load
    // s = s0 + lane (coalesced 140 B per row; halo 3 for P4's w+3)
    if (lane < 35 && s0 + lane < S_) {
        const int s = s0 + lane;
        #pragma unroll
        for (int k = 0; k < 32; ++k) {
            const int c = wv + k * 8;                     // 0..255
            tile[c][lane] = fm[((size_t)b * C_ + c) * S_ + s];
        }
    }
    __syncthreads();

    // compute + store: c = t & 255 (full channel width); halves split ls.
    const int c      = t & 255;
    const int lsBase = (t >> 8) * 16;         // 0 or 16
    #pragma unroll
    for (int j = 0; j < 16; ++j) {
        const int ls = lsBase + j;
        const int s  = s0 + ls;
        if (s < S_) {                         // uniform guard
            const int w   = s % W_;           // uniform per iteration
            int rem = W_ - 1 - w;             // valid same-row neighbors
            if (rem > 3) rem = 3;
            const float v0 = tile[c][ls];
            float p2 = (rem >= 1) ? fmaxf(v0, tile[c][ls + 1]) : v0;
            float p4 = p2;
            if (rem >= 2) p4 = fmaxf(p4, tile[c][ls + 2]);
            if (rem >= 3) p4 = fmaxf(p4, tile[c][ls + 3]);

            const size_t o = ((size_t)b * S_ + s) * C_ + c;
            fmT[o] = v0;                      // 1024 B contiguous per (s, table)
            P2[o]  = p2;
            P4[o]  = p4;
        }
    }
}

// ---------------------------------------------------------------------------
// Block-uniform ROI decode (SPATIAL_SCALE == 1.0); matches reference exactly.
// ---------------------------------------------------------------------------
__device__ __forceinline__ void roi_decode(const float* __restrict__ rois, int r,
                                           int& b, int& x0, int& y0,
                                           int& roi_w, int& roi_h)
{
    const float* rp = rois + r * 5;
    b = (int)rp[4];                          // trunc, matches astype(int32)
    // jnp.round == round-half-to-even == rintf
    x0      = (int)rintf(rp[0]);
    y0      = (int)rintf(rp[1]);
    int x1  = (int)rintf(rp[2]);
    int y1  = (int)rintf(rp[3]);
    x0 = min(max(x0, 0), W_ - 1);
    x1 = min(max(x1, 0), W_ - 1);
    y0 = min(max(y0, 0), H_ - 1);
    y1 = min(max(y1, 0), H_ - 1);
    x1 = max(x1, x0 + 1);
    y1 = max(y1, y0 + 1);
    roi_w = x1 - x0;                         // >= 1  (bin widths  <= 8)
    roi_h = y1 - y0;                         // >= 1  (bin heights <= 8)
}

// ---------------------------------------------------------------------------
// K2 (byte-identical to R10's proven version): branchless per-bin pooling,
// WH = block-uniform max bin height. Span tables: sp=4/2/1 -> anchors ws and
// we-sp cover exactly [ws,we) for any ww 1..8. Rows: min(hs+kh, he-1)
// in-window clamp. UNROLL 2: <= 32 values in flight. int32 offsets.
// ---------------------------------------------------------------------------
template<int WH>
__device__ __forceinline__ void pool_bins(
    const float* __restrict__ fmT, const float* __restrict__ P2,
    const float* __restrict__ P4, float* __restrict__ buf,
    int wv, int lane, int imgC,
    int x0, int y0, int roi_w, int roi_h)
{
    const int start = wv * 12 + (wv ? 1 : 0);
    const int qlast = wv * 12 + 12;

    #pragma unroll 2
    for (int k = 0; k < 13; ++k) {
        int q = start + k;
        q = (q > qlast) ? qlast : q;
        const int ph = q / PW_;
        const int pw = q - ph * PW_;
        const int ws = x0 + (pw * roi_w) / PW_;
        const int we = x0 + ((pw + 1) * roi_w + PW_ - 1) / PW_;
        const int hs = y0 + (ph * roi_h) / PH_;
        const int he = y0 + ((ph + 1) * roi_h + PH_ - 1) / PH_;
        const int ww = we - ws;              // 1..8

        const int sp = (ww >= 4) ? 4 : ((ww >= 2) ? 2 : 1);
        const float* tb = (ww >= 4) ? P4 : ((ww >= 2) ? P2 : fmT);
        const int colB = we - sp;

        float va[WH], vb[WH];
        #pragma unroll
        for (int kh = 0; kh < WH; ++kh) {
            int row = hs + kh;
            row = (row > he - 1) ? (he - 1) : row;        // clamp (in-window)
            const int ro = imgC + row * (W_ * C_);
            va[kh] = tb[ro + ws * C_];
            vb[kh] = tb[ro + colB * C_];
        }
        float m = -FLT_MAX;
        #pragma unroll
        for (int kh = 0; kh < WH; ++kh)
            m = fmaxf(m, fmaxf(va[kh], vb[kh]));

        buf[q * 65 + lane] = m;
    }
}

__global__ __launch_bounds__(256) void roi_pool_tables(
    const float* __restrict__ fmT,   // [B, S, C]
    const float* __restrict__ P2,    // [B, S, C]
    const float* __restrict__ P4,    // [B, S, C]
    const float* __restrict__ rois,  // [R, 5]
    float* __restrict__ out)         // [R, C, Q]
{
    __shared__ float buf[Q_ * 65];           // 12740 B

    // XCD-chunked swizzle (1200 % 8 == 0 -> bijective)
    const int bid = blockIdx.x;
    const int swz = (bid & 7) * (NWG_POOL / 8) + (bid >> 3);
    const int r   = swz >> 2;
    const int c0  = (swz & (NCQ - 1)) * CQ_;

    const int t    = threadIdx.x;
    const int wv   = t >> 6;
    const int lane = t & 63;

    int b, x0, y0, roi_w, roi_h;
    roi_decode(rois, r, b, x0, y0, roi_w, roi_h);

    // exact block-uniform max bin height
    int whmax = 1;
    #pragma unroll
    for (int i = 0; i < PH_; ++i) {
        const int hs = (i * roi_h) / PH_;
        const int he = ((i + 1) * roi_h + PH_ - 1) / PH_;
        whmax = max(whmax, he - hs);
    }

    const int imgC = b * SC_ + c0 + lane;    // < 2.56M, fits int32

    switch (whmax) {                         // block-uniform dispatch
        case 1: pool_bins<1>(fmT, P2, P4, buf, wv, lane, imgC, x0, y0, roi_w, roi_h); break;
        case 2: pool_bins<2>(fmT, P2, P4, buf, wv, lane, imgC, x0, y0, roi_w, roi_h); break;
        case 3: pool_bins<3>(fmT, P2, P4, buf, wv, lane, imgC, x0, y0, roi_w, roi_h); break;
        case 4: pool_bins<4>(fmT, P2, P4, buf, wv, lane, imgC, x0, y0, roi_w, roi_h); break;
        case 5: pool_bins<5>(fmT, P2, P4, buf, wv, lane, imgC, x0, y0, roi_w, roi_h); break;
        case 6: pool_bins<6>(fmT, P2, P4, buf, wv, lane, imgC, x0, y0, roi_w, roi_h); break;
        case 7: pool_bins<7>(fmT, P2, P4, buf, wv, lane, imgC, x0, y0, roi_w, roi_h); break;
        default: pool_bins<8>(fmT, P2, P4, buf, wv, lane, imgC, x0, y0, roi_w, roi_h); break;
    }
    __syncthreads();

    // block-exclusive coalesced write: out[r, c0..c0+64, 0..49)
    float* outp = out + ((size_t)r * C_ + c0) * Q_;
    #pragma unroll
    for (int k = 0; k < 13; ++k) {
        const int e = k * 256 + t;
        if (e < CQ_ * Q_) {
            const int cl = e / Q_;
            const int q  = e - cl * Q_;
            outp[e] = buf[q * 65 + cl];
        }
    }
}

// ---------------------------------------------------------------------------
// Fallback (ws too small): round-1 thread-per-output kernel (proven, 42.7 us).
// ---------------------------------------------------------------------------
__global__ __launch_bounds__(256) void roi_pool_naive(
    const float* __restrict__ fm,    // [B, C, H, W]
    const float* __restrict__ rois,
    float* __restrict__ out)
{
    const int total = R_ * C_ * Q_;
    int t = blockIdx.x * blockDim.x + threadIdx.x;
    if (t >= total) return;
    int q   = t % Q_;
    int tmp = t / Q_;
    int pw  = q % PW_;
    int ph  = q / PW_;
    int c   = tmp % C_;
    int r   = tmp / C_;

    int b, x0, y0, roi_w, roi_h;
    roi_decode(rois, r, b, x0, y0, roi_w, roi_h);

    const int ws = x0 + (pw * roi_w) / PW_;
    const int we = x0 + ((pw + 1) * roi_w + PW_ - 1) / PW_;
    const int hs = y0 + (ph * roi_h) / PH_;
    const int he = y0 + ((ph + 1) * roi_h + PH_ - 1) / PH_;

    const float* p = fm + ((size_t)(b * C_ + c)) * S_;
    float m = -FLT_MAX;
    for (int h = hs; h < he; ++h)
        for (int w = ws; w < we; ++w)
            m = fmaxf(m, p[h * W_ + w]);
    out[t] = m;
}

extern "C" void kernel_launch(void* const* d_in, const int* in_sizes, int n_in,
                              void* d_out, int out_size, void* d_ws, size_t ws_size,
                              hipStream_t stream)
{
    const float* fm   = (const float*)d_in[0];  // [4,256,50,50]
    const float* rois = (const float*)d_in[1];  // [300,5]
    float* out        = (float*)d_out;          // [300,256,7,7]

    const size_t NEED = 3 * (size_t)ARRN * sizeof(float);   // 30.72 MB

    if (ws_size >= NEED) {
        float* fmT = (float*)d_ws;
        float* P2  = fmT + ARRN;
        float* P4  = P2 + ARRN;
        {
            dim3 grid(79, B_);                   // 79 s-tiles x 4 batch
            transpose_tables<<<grid, 512, 0, stream>>>(fm, fmT, P2, P4);
        }
        roi_pool_tables<<<NWG_POOL, 256, 0, stream>>>(fmT, P2, P4, rois, out);
    } else {
        const int total = R_ * C_ * Q_;
        roi_pool_naive<<<(total + 255) / 256, 256, 0, stream>>>(fm, rois, out);
    }
}